// Round 9
// baseline (287.113 us; speedup 1.0000x reference)
//
#include <hip/hip_runtime.h>

// CP tensor log-likelihood. T=512, NL=10000, NM=5000, RANK=32, NNZ=10M.
//
// R8 post-mortem: gather duty-cycle bound — per iteration the wave issues
// gathers, drains vmcnt, then computes with ZERO requests in flight (~4%
// outstanding duty). R9: 2-deep ping-pong pipeline — issue batch B's
// gathers before computing batch A, so every wave keeps ~8 gather instrs
// in flight continuously. Batch = 4 nnz to hold VGPR <= 128 (occupancy
// cliff). fp8 factors, Um in LDS, Ws L1-resident, Ul via L2 (unchanged).
//
// ws layout (bytes):
//   [0, 1024)         per-block ll partials (256 floats)
//   [1024, 25600)     colsum partials (192 blocks x 32 floats)
//   [65536, +16384)   fp8 Ws
//   [81920, +320000)  fp8 Ul
//   [401920, +160000) fp8 Um

#define RANK 32
#define TPB 1024
#define NBLK 256
#define PTPB 256
#define CSBLK 192          // colsum blocks: 16 Ws, 112 Ul, 64 Um
#define CVTBLK 256
#define PREB (CSBLK + CVTBLK)
#define UM_LDS_BYTES 160000

typedef float f2v __attribute__((ext_vector_type(2)));

__device__ __forceinline__ float dot8_fp8(uint2 a, uint2 b, uint2 c) {
    f2v a0 = __builtin_amdgcn_cvt_pk_f32_fp8((int)a.x, false);
    f2v a1 = __builtin_amdgcn_cvt_pk_f32_fp8((int)a.x, true);
    f2v a2 = __builtin_amdgcn_cvt_pk_f32_fp8((int)a.y, false);
    f2v a3 = __builtin_amdgcn_cvt_pk_f32_fp8((int)a.y, true);
    f2v b0 = __builtin_amdgcn_cvt_pk_f32_fp8((int)b.x, false);
    f2v b1 = __builtin_amdgcn_cvt_pk_f32_fp8((int)b.x, true);
    f2v b2 = __builtin_amdgcn_cvt_pk_f32_fp8((int)b.y, false);
    f2v b3 = __builtin_amdgcn_cvt_pk_f32_fp8((int)b.y, true);
    f2v c0 = __builtin_amdgcn_cvt_pk_f32_fp8((int)c.x, false);
    f2v c1 = __builtin_amdgcn_cvt_pk_f32_fp8((int)c.x, true);
    f2v c2 = __builtin_amdgcn_cvt_pk_f32_fp8((int)c.y, false);
    f2v c3 = __builtin_amdgcn_cvt_pk_f32_fp8((int)c.y, true);
    float s = a0.x * b0.x * c0.x;
    s = fmaf(a0.y * b0.y, c0.y, s);
    s = fmaf(a1.x * b1.x, c1.x, s);
    s = fmaf(a1.y * b1.y, c1.y, s);
    s = fmaf(a2.x * b2.x, c2.x, s);
    s = fmaf(a2.y * b2.y, c2.y, s);
    s = fmaf(a3.x * b3.x, c3.x, s);
    s = fmaf(a3.y * b3.y, c3.y, s);
    return s;
}

__device__ __forceinline__ float sel4(int q, float a, float b, float c, float d) {
    return (q == 0) ? a : (q == 1) ? b : (q == 2) ? c : d;
}

// ---- prep: fp32-exact colsum partials + fp8 e4m3 conversion ----
__global__ void __launch_bounds__(PTPB)
prep_kernel(const float* __restrict__ Ws, int nWs,
            const float* __restrict__ Ul, int nUl,
            const float* __restrict__ Um, int nUm,
            float* __restrict__ csp,
            unsigned char* __restrict__ Wb, unsigned char* __restrict__ Ub,
            unsigned char* __restrict__ Mb) {
    const int tid = threadIdx.x;
    const int bid = blockIdx.x;
    if (bid < CSBLK) {
        __shared__ float sm[PTPB];
        const float* M;
        int nrows, b0, nb;
        if (bid < 16)       { M = Ws; nrows = nWs; b0 = 0;   nb = 16;  }
        else if (bid < 128) { M = Ul; nrows = nUl; b0 = 16;  nb = 112; }
        else                { M = Um; nrows = nUm; b0 = 128; nb = 64;  }
        const int c = tid & 31;
        const int g = tid >> 5;
        float p = 0.f;
        for (int r = (bid - b0) * 8 + g; r < nrows; r += nb * 8)
            p += M[r * RANK + c];
        sm[tid] = p;
        __syncthreads();
        if (tid < 128) sm[tid] += sm[tid + 128];
        __syncthreads();
        if (tid < 64) sm[tid] += sm[tid + 64];
        __syncthreads();
        if (tid < 32) csp[bid * 32 + tid] = sm[tid] + sm[tid + 32];
    } else {
        const int eW = nWs * RANK;              // 16384
        const int eU = nUl * RANK;              // 320000
        const int eM = nUm * RANK;              // 160000
        const int NQ = (eW + eU + eM) >> 2;
        int t = (bid - CSBLK) * PTPB + tid;
        for (int qd = t; qd < NQ; qd += CVTBLK * PTPB) {
            const int e = qd << 2;
            const float* src;
            unsigned char* dst;
            int off;
            if (e < eW)            { src = Ws; dst = Wb; off = e; }
            else if (e < eW + eU)  { src = Ul; dst = Ub; off = e - eW; }
            else                   { src = Um; dst = Mb; off = e - eW - eU; }
            const float4 f = *(const float4*)(src + off);
            int p = 0;
            p = __builtin_amdgcn_cvt_pk_fp8_f32(f.x, f.y, p, false);
            p = __builtin_amdgcn_cvt_pk_fp8_f32(f.z, f.w, p, true);
            ((int*)dst)[off >> 2] = p;
        }
    }
}

// ---- main: 4 lanes/nnz, 4 nnz/batch, 2-deep gather pipeline,
//      Um entirely in LDS, Ws via L1, Ul via L2 ----
__global__ void __launch_bounds__(TPB, 4)
nnz_kernel(const unsigned char* __restrict__ Wb,
           const unsigned char* __restrict__ Ub,
           const unsigned char* __restrict__ Mb,
           const float* __restrict__ vals,
           const int* __restrict__ s0, const int* __restrict__ s1,
           const int* __restrict__ s2, int nnz,
           float* __restrict__ llp,
           const float* __restrict__ WsF, const float* __restrict__ UlF,
           const float* __restrict__ UmF) {
    extern __shared__ unsigned char lum[];      // 160,000 B: all of fp8 Um
    const int tid = threadIdx.x;
    const int bid = blockIdx.x;

    {
        const uint4* src = (const uint4*)Mb;
        uint4* dst = (uint4*)lum;
        for (int t = tid; t < UM_LDS_BYTES / 16; t += TPB) dst[t] = src[t];
    }
    __syncthreads();

    const int q = tid & 3;
    const int qb = q * 8;                       // byte slice of 32B row
    const int gid = (bid * TPB + tid) >> 2;
    const int step = (NBLK * TPB) >> 2;         // 65536 groups
    const int nquads = nnz >> 2;

    float local = 0.f;

    // ---- prologue: load batch A indices, issue batch A gathers ----
    int n_a = gid;
    int n_b = gid + step;
    int4 icA;
    float4 vA;
    uint2 uA0, uA1, uA2, uA3;   // Ul rows (L2)
    uint2 wA0, wA1, wA2, wA3;   // Ws rows (L1)
    if (n_a < nquads) {
        const int n0 = n_a << 2;
        const int4 ia = *(const int4*)(s0 + n0);
        const int4 ib = *(const int4*)(s1 + n0);
        icA = *(const int4*)(s2 + n0);
        vA  = *(const float4*)(vals + n0);
        uA0 = *(const uint2*)(Ub + ib.x * 32 + qb);
        uA1 = *(const uint2*)(Ub + ib.y * 32 + qb);
        uA2 = *(const uint2*)(Ub + ib.z * 32 + qb);
        uA3 = *(const uint2*)(Ub + ib.w * 32 + qb);
        wA0 = *(const uint2*)(Wb + ia.x * 32 + qb);
        wA1 = *(const uint2*)(Wb + ia.y * 32 + qb);
        wA2 = *(const uint2*)(Wb + ia.z * 32 + qb);
        wA3 = *(const uint2*)(Wb + ia.w * 32 + qb);
    }

    while (n_a < nquads) {
        // ---- issue batch B (stays in flight across batch A's compute) ----
        int4 jc;
        float4 vB;
        uint2 uB0, uB1, uB2, uB3, wB0, wB1, wB2, wB3;
        if (n_b < nquads) {
            const int m0 = n_b << 2;
            const int4 ja = *(const int4*)(s0 + m0);
            const int4 jb = *(const int4*)(s1 + m0);
            jc = *(const int4*)(s2 + m0);
            vB = *(const float4*)(vals + m0);
            uB0 = *(const uint2*)(Ub + jb.x * 32 + qb);
            uB1 = *(const uint2*)(Ub + jb.y * 32 + qb);
            uB2 = *(const uint2*)(Ub + jb.z * 32 + qb);
            uB3 = *(const uint2*)(Ub + jb.w * 32 + qb);
            wB0 = *(const uint2*)(Wb + ja.x * 32 + qb);
            wB1 = *(const uint2*)(Wb + ja.y * 32 + qb);
            wB2 = *(const uint2*)(Wb + ja.z * 32 + qb);
            wB3 = *(const uint2*)(Wb + ja.w * 32 + qb);
        }

        // ---- compute batch A (its gathers issued one iteration ago) ----
        const uint2 cA0 = *(const uint2*)(lum + icA.x * 32 + qb);
        const uint2 cA1 = *(const uint2*)(lum + icA.y * 32 + qb);
        const uint2 cA2 = *(const uint2*)(lum + icA.z * 32 + qb);
        const uint2 cA3 = *(const uint2*)(lum + icA.w * 32 + qb);

        float sA = dot8_fp8(wA0, uA0, cA0);
        float sB = dot8_fp8(wA1, uA1, cA1);
        float sC = dot8_fp8(wA2, uA2, cA2);
        float sD = dot8_fp8(wA3, uA3, cA3);

        sA += __shfl_xor(sA, 1, 64); sB += __shfl_xor(sB, 1, 64);
        sC += __shfl_xor(sC, 1, 64); sD += __shfl_xor(sD, 1, 64);
        sA += __shfl_xor(sA, 2, 64); sB += __shfl_xor(sB, 2, 64);
        sC += __shfl_xor(sC, 2, 64); sD += __shfl_xor(sD, 2, 64);

        const float sv = sel4(q, sA, sB, sC, sD);
        const float vv = sel4(q, vA.x, vA.y, vA.z, vA.w);
        local = fmaf(vv, __logf(fmaxf(sv, 1e-10f)), local);

        // ---- rotate B -> A ----
        n_a = n_b;
        n_b += step;
        icA = jc; vA = vB;
        uA0 = uB0; uA1 = uB1; uA2 = uB2; uA3 = uB3;
        wA0 = wB0; wA1 = wB1; wA2 = wB2; wA3 = wB3;
    }

    // tail (nnz % 4) in exact fp32 — negligible
    const int tail = nnz & 3;
    if (tail && bid == 0 && tid == 0) {
        for (int n = nnz - tail; n < nnz; ++n) {
            const int i = s0[n], j = s1[n], k = s2[n];
            float s = 0.f;
            for (int r = 0; r < RANK; ++r)
                s = fmaf(WsF[i * RANK + r] * UlF[j * RANK + r], UmF[k * RANK + r], s);
            local = fmaf(vals[n], __logf(fmaxf(s, 1e-10f)), local);
        }
    }

    // block reduction (16 waves) -> llp[bid]
#pragma unroll
    for (int off = 32; off > 0; off >>= 1)
        local += __shfl_down(local, off, 64);
    __shared__ float wsum[16];
    const int lane = tid & 63;
    const int wid = tid >> 6;
    if (lane == 0) wsum[wid] = local;
    __syncthreads();
    if (tid == 0) {
        float t = 0.f;
#pragma unroll
        for (int i = 0; i < 16; ++i) t += wsum[i];
        llp[bid] = t;
    }
}

__global__ void finalize_kernel(const float* __restrict__ llp,
                                const float* __restrict__ csp,
                                int nWs, float* __restrict__ out) {
    __shared__ float sm[PTPB];
    const int tid = threadIdx.x;
    float l = (tid < NBLK) ? llp[tid] : 0.f;
    sm[tid] = l;
    __syncthreads();
    if (tid < 128) sm[tid] += sm[tid + 128];
    __syncthreads();
    if (tid < 64) sm[tid] += sm[tid + 64];
    __syncthreads();
    if (tid < 32) sm[tid] += sm[tid + 32];
    __syncthreads();
    if (tid < 32) {
        float ll = sm[tid];
#pragma unroll
        for (int off = 16; off > 0; off >>= 1) ll += __shfl_down(ll, off, 32);
        float pw = 0.f, pu = 0.f, pm = 0.f;
        for (int b = 0; b < 16; ++b)    pw += csp[b * 32 + tid];
        for (int b = 16; b < 128; ++b)  pu += csp[b * 32 + tid];
        for (int b = 128; b < 192; ++b) pm += csp[b * 32 + tid];
        float p = pw * pu * pm;
#pragma unroll
        for (int off = 16; off > 0; off >>= 1) p += __shfl_down(p, off, 32);
        if (tid == 0)
            out[0] = (p - ll) / (float)nWs;    // -((ll_sum - sum_M)/T)
    }
}

extern "C" void kernel_launch(void* const* d_in, const int* in_sizes, int n_in,
                              void* d_out, int out_size, void* d_ws, size_t ws_size,
                              hipStream_t stream) {
    const float* Ws   = (const float*)d_in[0];
    const float* Ul   = (const float*)d_in[1];
    const float* Um   = (const float*)d_in[2];
    const float* vals = (const float*)d_in[3];
    const int*   s0   = (const int*)d_in[4];
    const int*   s1   = (const int*)d_in[5];
    const int*   s2   = (const int*)d_in[6];
    float* out = (float*)d_out;
    const int nnz = in_sizes[3];
    const int nWs = in_sizes[0] / RANK;   // 512
    const int nUl = in_sizes[1] / RANK;   // 10000
    const int nUm = in_sizes[2] / RANK;   // 5000

    char* wsb = (char*)d_ws;
    float* llp = (float*)wsb;                               // 256 floats
    float* csp = llp + NBLK;                                // 192*32 floats
    unsigned char* Wb = (unsigned char*)(wsb + 65536);      // fp8 Ws  (16384 B)
    unsigned char* Ub = Wb + (size_t)nWs * RANK;            // fp8 Ul  (320000 B)
    unsigned char* Mb = Ub + (size_t)nUl * RANK;            // fp8 Um  (160000 B)

    (void)hipFuncSetAttribute((const void*)nnz_kernel,
                              hipFuncAttributeMaxDynamicSharedMemorySize,
                              UM_LDS_BYTES);

    prep_kernel<<<PREB, PTPB, 0, stream>>>(Ws, nWs, Ul, nUl, Um, nUm, csp, Wb, Ub, Mb);
    nnz_kernel<<<NBLK, TPB, UM_LDS_BYTES, stream>>>(Wb, Ub, Mb, vals, s0, s1, s2,
                                                    nnz, llp, Ws, Ul, Um);
    finalize_kernel<<<1, PTPB, 0, stream>>>(llp, csp, nWs, out);
}

// Round 10
// 281.274 us; speedup vs baseline: 1.0208x; 1.0208x over previous
//
#include <hip/hip_runtime.h>

// CP tensor log-likelihood. T=512, NL=10000, NM=5000, RANK=32, NNZ=10M.
//
// R9 post-mortem: compiler sank the ping-pong loads (VGPR 60->44) — pipeline
// never materialized. R10: 3-stage rotation with sched_barrier(0) pinning the
// issue cluster (B-gathers + C-streams) above the A-compute cluster. A's
// gathers are a full iteration old at first use -> vmcnt waits only past the
// ~19 newer B/C loads, keeping them in flight through compute.
// fp8 factors, Um in LDS (160KB), Ws L1-resident, Ul via L2.
//
// ws layout (bytes):
//   [0, 1024)         per-block ll partials (256 floats)
//   [1024, 25600)     colsum partials (192 blocks x 32 floats)
//   [65536, +16384)   fp8 Ws
//   [81920, +320000)  fp8 Ul
//   [401920, +160000) fp8 Um

#define RANK 32
#define TPB 1024
#define NBLK 256
#define PTPB 256
#define CSBLK 192          // colsum blocks: 16 Ws, 112 Ul, 64 Um
#define CVTBLK 256
#define PREB (CSBLK + CVTBLK)
#define UM_LDS_BYTES 160000

typedef float f2v __attribute__((ext_vector_type(2)));

__device__ __forceinline__ float dot8_fp8(uint2 a, uint2 b, uint2 c) {
    f2v a0 = __builtin_amdgcn_cvt_pk_f32_fp8((int)a.x, false);
    f2v a1 = __builtin_amdgcn_cvt_pk_f32_fp8((int)a.x, true);
    f2v a2 = __builtin_amdgcn_cvt_pk_f32_fp8((int)a.y, false);
    f2v a3 = __builtin_amdgcn_cvt_pk_f32_fp8((int)a.y, true);
    f2v b0 = __builtin_amdgcn_cvt_pk_f32_fp8((int)b.x, false);
    f2v b1 = __builtin_amdgcn_cvt_pk_f32_fp8((int)b.x, true);
    f2v b2 = __builtin_amdgcn_cvt_pk_f32_fp8((int)b.y, false);
    f2v b3 = __builtin_amdgcn_cvt_pk_f32_fp8((int)b.y, true);
    f2v c0 = __builtin_amdgcn_cvt_pk_f32_fp8((int)c.x, false);
    f2v c1 = __builtin_amdgcn_cvt_pk_f32_fp8((int)c.x, true);
    f2v c2 = __builtin_amdgcn_cvt_pk_f32_fp8((int)c.y, false);
    f2v c3 = __builtin_amdgcn_cvt_pk_f32_fp8((int)c.y, true);
    float s = a0.x * b0.x * c0.x;
    s = fmaf(a0.y * b0.y, c0.y, s);
    s = fmaf(a1.x * b1.x, c1.x, s);
    s = fmaf(a1.y * b1.y, c1.y, s);
    s = fmaf(a2.x * b2.x, c2.x, s);
    s = fmaf(a2.y * b2.y, c2.y, s);
    s = fmaf(a3.x * b3.x, c3.x, s);
    s = fmaf(a3.y * b3.y, c3.y, s);
    return s;
}

__device__ __forceinline__ float sel4(int q, float a, float b, float c, float d) {
    return (q == 0) ? a : (q == 1) ? b : (q == 2) ? c : d;
}

// ---- prep: fp32-exact colsum partials + fp8 e4m3 conversion ----
__global__ void __launch_bounds__(PTPB)
prep_kernel(const float* __restrict__ Ws, int nWs,
            const float* __restrict__ Ul, int nUl,
            const float* __restrict__ Um, int nUm,
            float* __restrict__ csp,
            unsigned char* __restrict__ Wb, unsigned char* __restrict__ Ub,
            unsigned char* __restrict__ Mb) {
    const int tid = threadIdx.x;
    const int bid = blockIdx.x;
    if (bid < CSBLK) {
        __shared__ float sm[PTPB];
        const float* M;
        int nrows, b0, nb;
        if (bid < 16)       { M = Ws; nrows = nWs; b0 = 0;   nb = 16;  }
        else if (bid < 128) { M = Ul; nrows = nUl; b0 = 16;  nb = 112; }
        else                { M = Um; nrows = nUm; b0 = 128; nb = 64;  }
        const int c = tid & 31;
        const int g = tid >> 5;
        float p = 0.f;
        for (int r = (bid - b0) * 8 + g; r < nrows; r += nb * 8)
            p += M[r * RANK + c];
        sm[tid] = p;
        __syncthreads();
        if (tid < 128) sm[tid] += sm[tid + 128];
        __syncthreads();
        if (tid < 64) sm[tid] += sm[tid + 64];
        __syncthreads();
        if (tid < 32) csp[bid * 32 + tid] = sm[tid] + sm[tid + 32];
    } else {
        const int eW = nWs * RANK;              // 16384
        const int eU = nUl * RANK;              // 320000
        const int eM = nUm * RANK;              // 160000
        const int NQ = (eW + eU + eM) >> 2;
        int t = (bid - CSBLK) * PTPB + tid;
        for (int qd = t; qd < NQ; qd += CVTBLK * PTPB) {
            const int e = qd << 2;
            const float* src;
            unsigned char* dst;
            int off;
            if (e < eW)            { src = Ws; dst = Wb; off = e; }
            else if (e < eW + eU)  { src = Ul; dst = Ub; off = e - eW; }
            else                   { src = Um; dst = Mb; off = e - eW - eU; }
            const float4 f = *(const float4*)(src + off);
            int p = 0;
            p = __builtin_amdgcn_cvt_pk_fp8_f32(f.x, f.y, p, false);
            p = __builtin_amdgcn_cvt_pk_fp8_f32(f.z, f.w, p, true);
            ((int*)dst)[off >> 2] = p;
        }
    }
}

// ---- main: 4 lanes/nnz, 4 nnz/batch, 3-stage pinned pipeline,
//      Um entirely in LDS, Ws via L1, Ul via L2 ----
__global__ void __launch_bounds__(TPB, 4)
nnz_kernel(const unsigned char* __restrict__ Wb,
           const unsigned char* __restrict__ Ub,
           const unsigned char* __restrict__ Mb,
           const float* __restrict__ vals,
           const int* __restrict__ s0, const int* __restrict__ s1,
           const int* __restrict__ s2, int nnz,
           float* __restrict__ llp,
           const float* __restrict__ WsF, const float* __restrict__ UlF,
           const float* __restrict__ UmF) {
    extern __shared__ unsigned char lum[];      // 160,000 B: all of fp8 Um
    const int tid = threadIdx.x;
    const int bid = blockIdx.x;

    {
        const uint4* src = (const uint4*)Mb;
        uint4* dst = (uint4*)lum;
        for (int t = tid; t < UM_LDS_BYTES / 16; t += TPB) dst[t] = src[t];
    }
    __syncthreads();

    const int q = tid & 3;
    const int qb = q * 8;                       // byte slice of 32B row
    const int gid = (bid * TPB + tid) >> 2;
    const int step = (NBLK * TPB) >> 2;         // 65536 groups
    const int nquads = nnz >> 2;

    float local = 0.f;

    if (nquads > 0) {
        // ---- pipeline state ----
        int n_a = gid;              // batch being computed
        int n_b = gid + step;       // batch whose gathers issue this iter
        int4 icA; float4 vA;                        // A: Um idx + vals
        uint2 gu0, gu1, gu2, gu3, gw0, gw1, gw2, gw3;   // A gather results
        int4 iaB, ibB, icB; float4 vB;              // B: indices ready

        {
            const int nacl = (n_a < nquads) ? n_a : (nquads - 1);
            const int a0 = nacl << 2;
            const int4 iaA = *(const int4*)(s0 + a0);
            const int4 ibA = *(const int4*)(s1 + a0);
            icA = *(const int4*)(s2 + a0);
            vA  = *(const float4*)(vals + a0);
            gu0 = *(const uint2*)(Ub + ibA.x * 32 + qb);
            gu1 = *(const uint2*)(Ub + ibA.y * 32 + qb);
            gu2 = *(const uint2*)(Ub + ibA.z * 32 + qb);
            gu3 = *(const uint2*)(Ub + ibA.w * 32 + qb);
            gw0 = *(const uint2*)(Wb + iaA.x * 32 + qb);
            gw1 = *(const uint2*)(Wb + iaA.y * 32 + qb);
            gw2 = *(const uint2*)(Wb + iaA.z * 32 + qb);
            gw3 = *(const uint2*)(Wb + iaA.w * 32 + qb);
            const int nbcl = (n_b < nquads) ? n_b : (nquads - 1);
            const int b0 = nbcl << 2;
            iaB = *(const int4*)(s0 + b0);
            ibB = *(const int4*)(s1 + b0);
            icB = *(const int4*)(s2 + b0);
            vB  = *(const float4*)(vals + b0);
        }

        while (n_a < nquads) {
            // ---- issue cluster: batch-B gathers (indices in regs, no wait) ----
            uint2 hu0 = *(const uint2*)(Ub + ibB.x * 32 + qb);
            uint2 hu1 = *(const uint2*)(Ub + ibB.y * 32 + qb);
            uint2 hu2 = *(const uint2*)(Ub + ibB.z * 32 + qb);
            uint2 hu3 = *(const uint2*)(Ub + ibB.w * 32 + qb);
            uint2 hw0 = *(const uint2*)(Wb + iaB.x * 32 + qb);
            uint2 hw1 = *(const uint2*)(Wb + iaB.y * 32 + qb);
            uint2 hw2 = *(const uint2*)(Wb + iaB.z * 32 + qb);
            uint2 hw3 = *(const uint2*)(Wb + iaB.w * 32 + qb);
            // ---- stream batch-C indices/vals (clamped, no guard) ----
            const int n_c = n_b + step;
            const int nccl = (n_c < nquads) ? n_c : (nquads - 1);
            const int c0 = nccl << 2;
            const int4 iaC = *(const int4*)(s0 + c0);
            const int4 ibC = *(const int4*)(s1 + c0);
            const int4 icC = *(const int4*)(s2 + c0);
            const float4 vC = *(const float4*)(vals + c0);

            __builtin_amdgcn_sched_barrier(0);  // pin: nothing crosses

            // ---- compute batch A (gathers issued one iteration ago) ----
            const uint2 cA0 = *(const uint2*)(lum + icA.x * 32 + qb);
            const uint2 cA1 = *(const uint2*)(lum + icA.y * 32 + qb);
            const uint2 cA2 = *(const uint2*)(lum + icA.z * 32 + qb);
            const uint2 cA3 = *(const uint2*)(lum + icA.w * 32 + qb);

            float sA = dot8_fp8(gw0, gu0, cA0);
            float sB = dot8_fp8(gw1, gu1, cA1);
            float sC = dot8_fp8(gw2, gu2, cA2);
            float sD = dot8_fp8(gw3, gu3, cA3);

            sA += __shfl_xor(sA, 1, 64); sB += __shfl_xor(sB, 1, 64);
            sC += __shfl_xor(sC, 1, 64); sD += __shfl_xor(sD, 1, 64);
            sA += __shfl_xor(sA, 2, 64); sB += __shfl_xor(sB, 2, 64);
            sC += __shfl_xor(sC, 2, 64); sD += __shfl_xor(sD, 2, 64);

            const float sv = sel4(q, sA, sB, sC, sD);
            const float vv = sel4(q, vA.x, vA.y, vA.z, vA.w);
            local = fmaf(vv, __logf(fmaxf(sv, 1e-10f)), local);

            // ---- rotate ----
            n_a = n_b; n_b = n_c;
            gu0 = hu0; gu1 = hu1; gu2 = hu2; gu3 = hu3;
            gw0 = hw0; gw1 = hw1; gw2 = hw2; gw3 = hw3;
            icA = icB; vA = vB;
            iaB = iaC; ibB = ibC; icB = icC; vB = vC;
        }
    }

    // tail (nnz % 4) in exact fp32 — negligible
    const int tail = nnz & 3;
    if (tail && bid == 0 && tid == 0) {
        for (int n = nnz - tail; n < nnz; ++n) {
            const int i = s0[n], j = s1[n], k = s2[n];
            float s = 0.f;
            for (int r = 0; r < RANK; ++r)
                s = fmaf(WsF[i * RANK + r] * UlF[j * RANK + r], UmF[k * RANK + r], s);
            local = fmaf(vals[n], __logf(fmaxf(s, 1e-10f)), local);
        }
    }

    // block reduction (16 waves) -> llp[bid]
#pragma unroll
    for (int off = 32; off > 0; off >>= 1)
        local += __shfl_down(local, off, 64);
    __shared__ float wsum[16];
    const int lane = tid & 63;
    const int wid = tid >> 6;
    if (lane == 0) wsum[wid] = local;
    __syncthreads();
    if (tid == 0) {
        float t = 0.f;
#pragma unroll
        for (int i = 0; i < 16; ++i) t += wsum[i];
        llp[bid] = t;
    }
}

__global__ void finalize_kernel(const float* __restrict__ llp,
                                const float* __restrict__ csp,
                                int nWs, float* __restrict__ out) {
    __shared__ float sm[PTPB];
    const int tid = threadIdx.x;
    float l = (tid < NBLK) ? llp[tid] : 0.f;
    sm[tid] = l;
    __syncthreads();
    if (tid < 128) sm[tid] += sm[tid + 128];
    __syncthreads();
    if (tid < 64) sm[tid] += sm[tid + 64];
    __syncthreads();
    if (tid < 32) sm[tid] += sm[tid + 32];
    __syncthreads();
    if (tid < 32) {
        float ll = sm[tid];
#pragma unroll
        for (int off = 16; off > 0; off >>= 1) ll += __shfl_down(ll, off, 32);
        float pw = 0.f, pu = 0.f, pm = 0.f;
        for (int b = 0; b < 16; ++b)    pw += csp[b * 32 + tid];
        for (int b = 16; b < 128; ++b)  pu += csp[b * 32 + tid];
        for (int b = 128; b < 192; ++b) pm += csp[b * 32 + tid];
        float p = pw * pu * pm;
#pragma unroll
        for (int off = 16; off > 0; off >>= 1) p += __shfl_down(p, off, 32);
        if (tid == 0)
            out[0] = (p - ll) / (float)nWs;    // -((ll_sum - sum_M)/T)
    }
}

extern "C" void kernel_launch(void* const* d_in, const int* in_sizes, int n_in,
                              void* d_out, int out_size, void* d_ws, size_t ws_size,
                              hipStream_t stream) {
    const float* Ws   = (const float*)d_in[0];
    const float* Ul   = (const float*)d_in[1];
    const float* Um   = (const float*)d_in[2];
    const float* vals = (const float*)d_in[3];
    const int*   s0   = (const int*)d_in[4];
    const int*   s1   = (const int*)d_in[5];
    const int*   s2   = (const int*)d_in[6];
    float* out = (float*)d_out;
    const int nnz = in_sizes[3];
    const int nWs = in_sizes[0] / RANK;   // 512
    const int nUl = in_sizes[1] / RANK;   // 10000
    const int nUm = in_sizes[2] / RANK;   // 5000

    char* wsb = (char*)d_ws;
    float* llp = (float*)wsb;                               // 256 floats
    float* csp = llp + NBLK;                                // 192*32 floats
    unsigned char* Wb = (unsigned char*)(wsb + 65536);      // fp8 Ws  (16384 B)
    unsigned char* Ub = Wb + (size_t)nWs * RANK;            // fp8 Ul  (320000 B)
    unsigned char* Mb = Ub + (size_t)nUl * RANK;            // fp8 Um  (160000 B)

    (void)hipFuncSetAttribute((const void*)nnz_kernel,
                              hipFuncAttributeMaxDynamicSharedMemorySize,
                              UM_LDS_BYTES);

    prep_kernel<<<PREB, PTPB, 0, stream>>>(Ws, nWs, Ul, nUl, Um, nUm, csp, Wb, Ub, Mb);
    nnz_kernel<<<NBLK, TPB, UM_LDS_BYTES, stream>>>(Wb, Ub, Mb, vals, s0, s1, s2,
                                                    nnz, llp, Ws, Ul, Um);
    finalize_kernel<<<1, PTPB, 0, stream>>>(llp, csp, nWs, out);
}

// Round 11
// 260.193 us; speedup vs baseline: 1.1035x; 1.0810x over previous
//
#include <hip/hip_runtime.h>

// CP tensor log-likelihood. T=512, NL=10000, NM=5000, RANK=32, NNZ=10M.
//
// R10 post-mortem: ~4.3-5 CU-cycles per divergent vector-memory REQUEST is
// invariant across 5 structures (TA/L1 request-processing ceiling). Only
// requests/nnz moves the needle. R11: Ws (fp8, 16KB) AND Um rows [0,4600)
// (fp8, 143.75KB) both in LDS (163,584B dynamic, exactly fits 160KiB with
// 64B static); ~8% Um-overflow rows via masked global fallback. Global
// requests/nnz: Ul 1.0 + Um-overflow 0.08 = 1.08 (was 2).
//
// ws layout (bytes):
//   [0, 1024)         per-block ll partials (256 floats)
//   [1024, 25600)     colsum partials (192 blocks x 32 floats)
//   [65536, +16384)   fp8 Ws
//   [81920, +320000)  fp8 Ul
//   [401920, +160000) fp8 Um

#define RANK 32
#define TPB 1024
#define NBLK 256
#define PTPB 256
#define CSBLK 192          // colsum blocks: 16 Ws, 112 Ul, 64 Um
#define CVTBLK 256
#define PREB (CSBLK + CVTBLK)
#define KCUT 4600                       // Um rows resident in LDS
#define WS_LDS_BYTES 16384
#define UM_LDS_BYTES (KCUT * 32)        // 147200
#define DYN_LDS_BYTES (WS_LDS_BYTES + UM_LDS_BYTES)   // 163584

typedef float f2v __attribute__((ext_vector_type(2)));

__device__ __forceinline__ float dot8_fp8(uint2 a, uint2 b, uint2 c) {
    f2v a0 = __builtin_amdgcn_cvt_pk_f32_fp8((int)a.x, false);
    f2v a1 = __builtin_amdgcn_cvt_pk_f32_fp8((int)a.x, true);
    f2v a2 = __builtin_amdgcn_cvt_pk_f32_fp8((int)a.y, false);
    f2v a3 = __builtin_amdgcn_cvt_pk_f32_fp8((int)a.y, true);
    f2v b0 = __builtin_amdgcn_cvt_pk_f32_fp8((int)b.x, false);
    f2v b1 = __builtin_amdgcn_cvt_pk_f32_fp8((int)b.x, true);
    f2v b2 = __builtin_amdgcn_cvt_pk_f32_fp8((int)b.y, false);
    f2v b3 = __builtin_amdgcn_cvt_pk_f32_fp8((int)b.y, true);
    f2v c0 = __builtin_amdgcn_cvt_pk_f32_fp8((int)c.x, false);
    f2v c1 = __builtin_amdgcn_cvt_pk_f32_fp8((int)c.x, true);
    f2v c2 = __builtin_amdgcn_cvt_pk_f32_fp8((int)c.y, false);
    f2v c3 = __builtin_amdgcn_cvt_pk_f32_fp8((int)c.y, true);
    float s = a0.x * b0.x * c0.x;
    s = fmaf(a0.y * b0.y, c0.y, s);
    s = fmaf(a1.x * b1.x, c1.x, s);
    s = fmaf(a1.y * b1.y, c1.y, s);
    s = fmaf(a2.x * b2.x, c2.x, s);
    s = fmaf(a2.y * b2.y, c2.y, s);
    s = fmaf(a3.x * b3.x, c3.x, s);
    s = fmaf(a3.y * b3.y, c3.y, s);
    return s;
}

__device__ __forceinline__ float sel4(int q, float a, float b, float c, float d) {
    return (q == 0) ? a : (q == 1) ? b : (q == 2) ? c : d;
}

// ---- prep: fp32-exact colsum partials + fp8 e4m3 conversion ----
__global__ void __launch_bounds__(PTPB)
prep_kernel(const float* __restrict__ Ws, int nWs,
            const float* __restrict__ Ul, int nUl,
            const float* __restrict__ Um, int nUm,
            float* __restrict__ csp,
            unsigned char* __restrict__ Wb, unsigned char* __restrict__ Ub,
            unsigned char* __restrict__ Mb) {
    const int tid = threadIdx.x;
    const int bid = blockIdx.x;
    if (bid < CSBLK) {
        __shared__ float sm[PTPB];
        const float* M;
        int nrows, b0, nb;
        if (bid < 16)       { M = Ws; nrows = nWs; b0 = 0;   nb = 16;  }
        else if (bid < 128) { M = Ul; nrows = nUl; b0 = 16;  nb = 112; }
        else                { M = Um; nrows = nUm; b0 = 128; nb = 64;  }
        const int c = tid & 31;
        const int g = tid >> 5;
        float p = 0.f;
        for (int r = (bid - b0) * 8 + g; r < nrows; r += nb * 8)
            p += M[r * RANK + c];
        sm[tid] = p;
        __syncthreads();
        if (tid < 128) sm[tid] += sm[tid + 128];
        __syncthreads();
        if (tid < 64) sm[tid] += sm[tid + 64];
        __syncthreads();
        if (tid < 32) csp[bid * 32 + tid] = sm[tid] + sm[tid + 32];
    } else {
        const int eW = nWs * RANK;              // 16384
        const int eU = nUl * RANK;              // 320000
        const int eM = nUm * RANK;              // 160000
        const int NQ = (eW + eU + eM) >> 2;
        int t = (bid - CSBLK) * PTPB + tid;
        for (int qd = t; qd < NQ; qd += CVTBLK * PTPB) {
            const int e = qd << 2;
            const float* src;
            unsigned char* dst;
            int off;
            if (e < eW)            { src = Ws; dst = Wb; off = e; }
            else if (e < eW + eU)  { src = Ul; dst = Ub; off = e - eW; }
            else                   { src = Um; dst = Mb; off = e - eW - eU; }
            const float4 f = *(const float4*)(src + off);
            int p = 0;
            p = __builtin_amdgcn_cvt_pk_fp8_f32(f.x, f.y, p, false);
            p = __builtin_amdgcn_cvt_pk_fp8_f32(f.z, f.w, p, true);
            ((int*)dst)[off >> 2] = p;
        }
    }
}

// ---- main: 4 lanes/nnz, 8 nnz/iter. Ws + Um[0,KCUT) in LDS; Ul global;
//      Um overflow (~8%) via masked global fallback ----
__global__ void __launch_bounds__(TPB, 4)
nnz_kernel(const unsigned char* __restrict__ Wb,
           const unsigned char* __restrict__ Ub,
           const unsigned char* __restrict__ Mb,
           const float* __restrict__ vals,
           const int* __restrict__ s0, const int* __restrict__ s1,
           const int* __restrict__ s2, int nnz,
           float* __restrict__ llp,
           const float* __restrict__ WsF, const float* __restrict__ UlF,
           const float* __restrict__ UmF) {
    extern __shared__ unsigned char dynlds[];   // [0,16384) Ws | [16384,+147200) Um
    const int tid = threadIdx.x;
    const int bid = blockIdx.x;

    // stage fp8 Ws + fp8 Um[0,KCUT) into LDS
    {
        const uint4* wsrc = (const uint4*)Wb;
        const uint4* msrc = (const uint4*)Mb;
        uint4* dst = (uint4*)dynlds;
        const int nw = WS_LDS_BYTES / 16;                   // 1024
        const int ntot = DYN_LDS_BYTES / 16;                // 10224
        for (int t = tid; t < ntot; t += TPB)
            dst[t] = (t < nw) ? wsrc[t] : msrc[t - nw];
    }
    __syncthreads();
    const unsigned char* lws = dynlds;
    const unsigned char* lum = dynlds + WS_LDS_BYTES;

    const int q = tid & 3;
    const int qb = q * 8;                       // byte slice of 32B row
    const int gid = (bid * TPB + tid) >> 2;
    const int ngroups = (NBLK * TPB) >> 2;      // 65536
    const int noct = nnz >> 3;

    float local = 0.f;

    int n8 = gid;
    int4 ia0, ia1, ib0, ib1, ic0, ic1;
    if (n8 < noct) {
        const int n0 = n8 << 3;
        ia0 = *(const int4*)(s0 + n0); ia1 = *(const int4*)(s0 + n0 + 4);
        ib0 = *(const int4*)(s1 + n0); ib1 = *(const int4*)(s1 + n0 + 4);
        ic0 = *(const int4*)(s2 + n0); ic1 = *(const int4*)(s2 + n0 + 4);
    }

    while (n8 < noct) {
        // 8 Ul gathers — the only mandatory global requests
        const uint2 bA = *(const uint2*)(Ub + ib0.x * 32 + qb);
        const uint2 bB = *(const uint2*)(Ub + ib0.y * 32 + qb);
        const uint2 bC = *(const uint2*)(Ub + ib0.z * 32 + qb);
        const uint2 bD = *(const uint2*)(Ub + ib0.w * 32 + qb);
        const uint2 bE = *(const uint2*)(Ub + ib1.x * 32 + qb);
        const uint2 bF = *(const uint2*)(Ub + ib1.y * 32 + qb);
        const uint2 bG = *(const uint2*)(Ub + ib1.z * 32 + qb);
        const uint2 bH = *(const uint2*)(Ub + ib1.w * 32 + qb);
        // 8 Ws reads from LDS
        const uint2 aA = *(const uint2*)(lws + ia0.x * 32 + qb);
        const uint2 aB = *(const uint2*)(lws + ia0.y * 32 + qb);
        const uint2 aC = *(const uint2*)(lws + ia0.z * 32 + qb);
        const uint2 aD = *(const uint2*)(lws + ia0.w * 32 + qb);
        const uint2 aE = *(const uint2*)(lws + ia1.x * 32 + qb);
        const uint2 aF = *(const uint2*)(lws + ia1.y * 32 + qb);
        const uint2 aG = *(const uint2*)(lws + ia1.z * 32 + qb);
        const uint2 aH = *(const uint2*)(lws + ia1.w * 32 + qb);
        // 8 Um reads: LDS if row < KCUT (92%), else global (8%)
        auto ldc = [&](int k) -> uint2 {
            if (k < KCUT) return *(const uint2*)(lum + k * 32 + qb);
            return *(const uint2*)(Mb + k * 32 + qb);
        };
        const uint2 cA = ldc(ic0.x);
        const uint2 cB = ldc(ic0.y);
        const uint2 cC = ldc(ic0.z);
        const uint2 cD = ldc(ic0.w);
        const uint2 cE = ldc(ic1.x);
        const uint2 cF = ldc(ic1.y);
        const uint2 cG = ldc(ic1.z);
        const uint2 cH = ldc(ic1.w);
        // vals (sequential, line-shared)
        const int n0 = n8 << 3;
        const float4 v40 = *(const float4*)(vals + n0);
        const float4 v41 = *(const float4*)(vals + n0 + 4);

        // prefetch next iteration's index streams
        const int n8n = n8 + ngroups;
        int4 ja0, ja1, jb0, jb1, jc0, jc1;
        if (n8n < noct) {
            const int m0 = n8n << 3;
            ja0 = *(const int4*)(s0 + m0); ja1 = *(const int4*)(s0 + m0 + 4);
            jb0 = *(const int4*)(s1 + m0); jb1 = *(const int4*)(s1 + m0 + 4);
            jc0 = *(const int4*)(s2 + m0); jc1 = *(const int4*)(s2 + m0 + 4);
        }

        float sA = dot8_fp8(aA, bA, cA);
        float sB = dot8_fp8(aB, bB, cB);
        float sC = dot8_fp8(aC, bC, cC);
        float sD = dot8_fp8(aD, bD, cD);
        float sE = dot8_fp8(aE, bE, cE);
        float sF = dot8_fp8(aF, bF, cF);
        float sG = dot8_fp8(aG, bG, cG);
        float sH = dot8_fp8(aH, bH, cH);

        sA += __shfl_xor(sA, 1, 64); sB += __shfl_xor(sB, 1, 64);
        sC += __shfl_xor(sC, 1, 64); sD += __shfl_xor(sD, 1, 64);
        sE += __shfl_xor(sE, 1, 64); sF += __shfl_xor(sF, 1, 64);
        sG += __shfl_xor(sG, 1, 64); sH += __shfl_xor(sH, 1, 64);
        sA += __shfl_xor(sA, 2, 64); sB += __shfl_xor(sB, 2, 64);
        sC += __shfl_xor(sC, 2, 64); sD += __shfl_xor(sD, 2, 64);
        sE += __shfl_xor(sE, 2, 64); sF += __shfl_xor(sF, 2, 64);
        sG += __shfl_xor(sG, 2, 64); sH += __shfl_xor(sH, 2, 64);

        const float sv0 = sel4(q, sA, sB, sC, sD);
        const float sv1 = sel4(q, sE, sF, sG, sH);
        const float vv0 = sel4(q, v40.x, v40.y, v40.z, v40.w);
        const float vv1 = sel4(q, v41.x, v41.y, v41.z, v41.w);
        local = fmaf(vv0, __logf(fmaxf(sv0, 1e-10f)), local);
        local = fmaf(vv1, __logf(fmaxf(sv1, 1e-10f)), local);

        n8 = n8n;
        ia0 = ja0; ia1 = ja1; ib0 = jb0; ib1 = jb1; ic0 = jc0; ic1 = jc1;
    }

    // tail (nnz % 8) in exact fp32 — negligible
    const int tail = nnz & 7;
    if (tail && bid == 0 && tid == 0) {
        for (int n = nnz - tail; n < nnz; ++n) {
            const int i = s0[n], j = s1[n], k = s2[n];
            float s = 0.f;
            for (int r = 0; r < RANK; ++r)
                s = fmaf(WsF[i * RANK + r] * UlF[j * RANK + r], UmF[k * RANK + r], s);
            local = fmaf(vals[n], __logf(fmaxf(s, 1e-10f)), local);
        }
    }

    // block reduction (16 waves) -> llp[bid]
#pragma unroll
    for (int off = 32; off > 0; off >>= 1)
        local += __shfl_down(local, off, 64);
    __shared__ float wsum[16];
    const int lane = tid & 63;
    const int wid = tid >> 6;
    if (lane == 0) wsum[wid] = local;
    __syncthreads();
    if (tid == 0) {
        float t = 0.f;
#pragma unroll
        for (int i = 0; i < 16; ++i) t += wsum[i];
        llp[bid] = t;
    }
}

__global__ void finalize_kernel(const float* __restrict__ llp,
                                const float* __restrict__ csp,
                                int nWs, float* __restrict__ out) {
    __shared__ float sm[PTPB];
    const int tid = threadIdx.x;
    float l = (tid < NBLK) ? llp[tid] : 0.f;
    sm[tid] = l;
    __syncthreads();
    if (tid < 128) sm[tid] += sm[tid + 128];
    __syncthreads();
    if (tid < 64) sm[tid] += sm[tid + 64];
    __syncthreads();
    if (tid < 32) sm[tid] += sm[tid + 32];
    __syncthreads();
    if (tid < 32) {
        float ll = sm[tid];
#pragma unroll
        for (int off = 16; off > 0; off >>= 1) ll += __shfl_down(ll, off, 32);
        float pw = 0.f, pu = 0.f, pm = 0.f;
        for (int b = 0; b < 16; ++b)    pw += csp[b * 32 + tid];
        for (int b = 16; b < 128; ++b)  pu += csp[b * 32 + tid];
        for (int b = 128; b < 192; ++b) pm += csp[b * 32 + tid];
        float p = pw * pu * pm;
#pragma unroll
        for (int off = 16; off > 0; off >>= 1) p += __shfl_down(p, off, 32);
        if (tid == 0)
            out[0] = (p - ll) / (float)nWs;    // -((ll_sum - sum_M)/T)
    }
}

extern "C" void kernel_launch(void* const* d_in, const int* in_sizes, int n_in,
                              void* d_out, int out_size, void* d_ws, size_t ws_size,
                              hipStream_t stream) {
    const float* Ws   = (const float*)d_in[0];
    const float* Ul   = (const float*)d_in[1];
    const float* Um   = (const float*)d_in[2];
    const float* vals = (const float*)d_in[3];
    const int*   s0   = (const int*)d_in[4];
    const int*   s1   = (const int*)d_in[5];
    const int*   s2   = (const int*)d_in[6];
    float* out = (float*)d_out;
    const int nnz = in_sizes[3];
    const int nWs = in_sizes[0] / RANK;   // 512
    const int nUl = in_sizes[1] / RANK;   // 10000
    const int nUm = in_sizes[2] / RANK;   // 5000

    char* wsb = (char*)d_ws;
    float* llp = (float*)wsb;                               // 256 floats
    float* csp = llp + NBLK;                                // 192*32 floats
    unsigned char* Wb = (unsigned char*)(wsb + 65536);      // fp8 Ws  (16384 B)
    unsigned char* Ub = Wb + (size_t)nWs * RANK;            // fp8 Ul  (320000 B)
    unsigned char* Mb = Ub + (size_t)nUl * RANK;            // fp8 Um  (160000 B)

    (void)hipFuncSetAttribute((const void*)nnz_kernel,
                              hipFuncAttributeMaxDynamicSharedMemorySize,
                              DYN_LDS_BYTES);

    prep_kernel<<<PREB, PTPB, 0, stream>>>(Ws, nWs, Ul, nUl, Um, nUm, csp, Wb, Ub, Mb);
    nnz_kernel<<<NBLK, TPB, DYN_LDS_BYTES, stream>>>(Wb, Ub, Mb, vals, s0, s1, s2,
                                                     nnz, llp, Ws, Ul, Um);
    finalize_kernel<<<1, PTPB, 0, stream>>>(llp, csp, nWs, out);
}